// Round 8
// baseline (155.361 us; speedup 1.0000x reference)
//
#include <hip/hip_runtime.h>
#include <hip/hip_bf16.h>

// R8: barrier-free bf16-MFMA flash attention.
// - pack_all (512 blocks): per-block LDS mask-scan (no separate build_idx
//   launch); K gathered into B-frag-contiguous tiles (one frag = 1KB
//   coalesced load); V transposed via LDS staging into the R7 frag layout.
// - attn_mfma7: K AND V fragments loaded global->VGPR (L2-hot), register
//   ping-pong prefetch one tile ahead, sP round-trip wave-private ->
//   ZERO __syncthreads in the K-loop; waves self-paced (kills the
//   barrier-lockstep that pinned R5-R7 at ~4700 cyc/iter).

#define B_    16
#define LQ_   2048
#define LK_   2048
#define DIM_  128
#define NTH   256
#define SCALE_ 0.08838834764831845f          // 1/sqrt(128)
#define LOG2E_ 1.4426950408889634f
#define SC2_   (SCALE_ * LOG2E_)
#define NEGBIG -1.0e9f
#define PS 72                                 // sP row stride (ushorts)

typedef __attribute__((ext_vector_type(8))) short bf16x8;
typedef __attribute__((ext_vector_type(4))) float f32x4;

static __device__ __forceinline__ unsigned short f2bf(float f) {
    unsigned int u = __builtin_bit_cast(unsigned int, f);
    u += 0x7fff + ((u >> 16) & 1);          // RNE
    return (unsigned short)(u >> 16);
}

// ---- single pre-pass: scan + K frag-pack + V transpose-pack ----
// K layout per tile (8192 ushorts): [wh][kt2][ks][quad][l15][8]
//   physical row r=wh*32+kt2*16+l15 holds LOGICAL key-slot wh*32+2*l15+kt2
//   (interleaved pairs so main's P pack stays a single v_perm+b32 write).
// V layout per tile: [wh][d][quad][8] : off = wh*4096 + d*32 + quad*8,
//   keys (logical) wh*32+quad*8+j.
__global__ __launch_bounds__(NTH) void pack_all(
    const float* __restrict__ K, const float* __restrict__ V,
    const float* __restrict__ Mk, int* __restrict__ hdr,
    unsigned short* __restrict__ Kb, unsigned short* __restrict__ Vtb)
{
    __shared__ int sIdx[2048];
    __shared__ int sc[256];
    __shared__ unsigned short sV[64 * 136];   // 17408 B, 8B-aligned rows

    const int tid = threadIdx.x;
    const int T = blockIdx.x;                 // batch*32 + ktile
    const int b = T >> 5, t = T & 31;

    // ---- mask scan (every block redundantly; mask is tiny & L2-hot) ----
    int keep[8], loc[8];
    int c = 0;
    #pragma unroll
    for (int j = 0; j < 8; ++j) {
        keep[j] = (Mk[tid * 8 + j] < 0.5f) ? 1 : 0;
        loc[j] = c;
        c += keep[j];
    }
    sc[tid] = c;
    __syncthreads();
    for (int off = 1; off < 256; off <<= 1) {
        int v = (tid >= off) ? sc[tid - off] : 0;
        __syncthreads();
        sc[tid] += v;
        __syncthreads();
    }
    const int base = sc[tid] - c;
    #pragma unroll
    for (int j = 0; j < 8; ++j)
        if (keep[j]) sIdx[base + loc[j]] = tid * 8 + j;
    __syncthreads();
    const int cnt = sc[255];
    if (T == 0 && tid == 0) hdr[0] = cnt;

    // ---- K gather -> frag layout (float4 reads, ushort4 writes) ----
    const float* Kbase = K + (size_t)b * LK_ * DIM_;
    unsigned short* kdst = Kb + (size_t)T * 8192;
    #pragma unroll
    for (int it = 0; it < 8; ++it) {
        int i = tid + it * NTH;               // 0..2047
        int sp = i >> 5, c4 = i & 31;         // physical row, float4 chunk
        int wh = sp >> 5, kt2 = (sp >> 4) & 1, l15 = sp & 15;
        int g = t * 64 + wh * 32 + 2 * l15 + kt2;   // logical slot
        int key = (g < cnt) ? sIdx[g] : 0;
        float4 v = *(const float4*)(Kbase + (size_t)key * DIM_ + c4 * 4);
        ushort4 h = { f2bf(v.x), f2bf(v.y), f2bf(v.z), f2bf(v.w) };
        int ks = c4 >> 3, quad = (c4 >> 1) & 3;
        *(ushort4*)(kdst + wh * 4096 + kt2 * 2048 + ks * 512 +
                    quad * 128 + l15 * 8 + (c4 & 1) * 4) = h;
    }

    // ---- V gather -> LDS (by logical slot), then transposed emit ----
    const float* Vbase = V + (size_t)b * LK_ * DIM_;
    #pragma unroll
    for (int it = 0; it < 8; ++it) {
        int i = tid + it * NTH;
        int slot = i >> 5, c4 = i & 31;       // logical slot
        int g = t * 64 + slot;
        int key = (g < cnt) ? sIdx[g] : 0;
        float4 v = *(const float4*)(Vbase + (size_t)key * DIM_ + c4 * 4);
        ushort4 h = { f2bf(v.x), f2bf(v.y), f2bf(v.z), f2bf(v.w) };
        *(ushort4*)&sV[slot * 136 + c4 * 4] = h;
    }
    __syncthreads();
    unsigned short* vdst = Vtb + (size_t)T * 8192;
    const int d = tid & 127, wh2 = tid >> 7;
    #pragma unroll
    for (int quad = 0; quad < 4; ++quad) {
        bf16x8 h;
        #pragma unroll
        for (int j = 0; j < 8; ++j)
            h[j] = (short)sV[(wh2 * 32 + quad * 8 + j) * 136 + d];
        *(bf16x8*)(vdst + wh2 * 4096 + d * 32 + quad * 8) = h;
    }
}

// ---- main kernel: no staging, no in-loop barriers ----
__global__ __launch_bounds__(NTH, 2) void attn_mfma7(
    const float* __restrict__ Q, const unsigned short* __restrict__ Kb,
    const unsigned short* __restrict__ Vtb, const int* __restrict__ hdr,
    float* __restrict__ O)
{
    __shared__ __align__(16) unsigned short sP[64 * PS];   // 9.2 KB (also Q staging)
    __shared__ float sO[64 * 128];                         // 32 KB (epilogue)
    __shared__ float sLp[64];

    const int tid  = threadIdx.x;
    const int w    = tid >> 6, lane = tid & 63;
    const int quad = lane >> 4, l15 = lane & 15;
    const int rg   = (w & 1) * 32;     // row group base
    const int wh   = w >> 1;           // key half
    const int kh   = wh * 32;

    const int bid = blockIdx.x;
    const int grp = bid >> 3;
    const int b   = (bid & 7) + 8 * (grp & 1);   // XCD-aware
    const int q0  = (grp >> 1) * 64;

    const int cnt = hdr[0];
    const int nIter2 = (((cnt + 63) >> 6) + 1) & ~1;   // even # of 64-key tiles

    bf16x8 vone;
    #pragma unroll
    for (int j = 0; j < 8; ++j) vone[j] = (short)0x3F80;

    const int voff = wh * 4096 + l15 * 32 + quad * 8;  // V frag base (ushorts)
    const int koff = wh * 4096 + lane * 8;             // K frag base (ushorts)

    // ---- stage Q (pre-scaled by SC2_) in two 32-row halves through sP ----
    bf16x8 aQ[2][4];
    {
        const float4* Qg = (const float4*)(Q + ((size_t)b * LQ_ + q0) * DIM_);
        #pragma unroll
        for (int h = 0; h < 2; ++h) {
            #pragma unroll
            for (int it = 0; it < 4; ++it) {
                int i2 = tid + it * NTH;
                int r = i2 >> 5, c4 = i2 & 31;
                float4 v = Qg[(h * 32 + r) * 32 + c4];
                ushort4 hh = { f2bf(v.x * SC2_), f2bf(v.y * SC2_),
                               f2bf(v.z * SC2_), f2bf(v.w * SC2_) };
                *(ushort4*)&sP[r * 128 + (((c4 >> 1) ^ (r & 15)) * 8) + (c4 & 1) * 4] = hh;
            }
            __syncthreads();
            if ((rg >> 5) == h) {
                #pragma unroll
                for (int rs = 0; rs < 2; ++rs)
                    #pragma unroll
                    for (int ks = 0; ks < 4; ++ks)
                        aQ[rs][ks] = *(const bf16x8*)&sP[(rs * 16 + l15) * 128 +
                                                         (((ks * 4 + quad) ^ l15) * 8)];
            }
            __syncthreads();
        }
    }

    f32x4 acc[2][8], lacc[2];
    #pragma unroll
    for (int rs = 0; rs < 2; ++rs) {
        lacc[rs] = (f32x4){0.f, 0.f, 0.f, 0.f};
        #pragma unroll
        for (int dt = 0; dt < 8; ++dt) acc[rs][dt] = (f32x4){0.f, 0.f, 0.f, 0.f};
    }

#define LOADKV(DK, DV, I) do {                                                 \
    const unsigned short* kbp = Kb + (size_t)(b * 32 + (I)) * 8192 + koff;     \
    _Pragma("unroll")                                                          \
    for (int kt2 = 0; kt2 < 2; ++kt2)                                          \
        _Pragma("unroll")                                                      \
        for (int ks = 0; ks < 4; ++ks)                                         \
            DK[kt2][ks] = *(const bf16x8*)(kbp + kt2 * 2048 + ks * 512);       \
    const unsigned short* vbp = Vtb + (size_t)(b * 32 + (I)) * 8192 + voff;    \
    _Pragma("unroll")                                                          \
    for (int dt = 0; dt < 8; ++dt)                                             \
        DV[dt] = *(const bf16x8*)(vbp + dt * 512);                             \
} while (0)

#define TILE_BODY(CK, CV, NK, NV, I) do {                                      \
    const int nxt = (I) + 1;                                                   \
    if (nxt < nIter2) LOADKV(NK, NV, nxt);                                     \
    f32x4 s_[2][2];                                                            \
    _Pragma("unroll")                                                          \
    for (int kt2 = 0; kt2 < 2; ++kt2) {                                        \
        f32x4 c0 = (f32x4){0.f,0.f,0.f,0.f}, c1 = (f32x4){0.f,0.f,0.f,0.f};   \
        _Pragma("unroll")                                                      \
        for (int ks = 0; ks < 4; ++ks) {                                       \
            c0 = __builtin_amdgcn_mfma_f32_16x16x32_bf16(aQ[0][ks], CK[kt2][ks], c0, 0,0,0); \
            c1 = __builtin_amdgcn_mfma_f32_16x16x32_bf16(aQ[1][ks], CK[kt2][ks], c1, 0,0,0); \
        }                                                                      \
        int slot = (I) * 64 + kh + 2 * l15 + kt2;                              \
        bool kept = slot < cnt;                                                \
        _Pragma("unroll")                                                      \
        for (int r = 0; r < 4; ++r) {                                          \
            s_[0][kt2][r] = kept ? c0[r] : -1.0e30f;                           \
            s_[1][kt2][r] = kept ? c1[r] : -1.0e30f;                           \
        }                                                                      \
    }                                                                          \
    _Pragma("unroll")                                                          \
    for (int rs = 0; rs < 2; ++rs)                                             \
        _Pragma("unroll")                                                      \
        for (int r = 0; r < 4; ++r) {                                          \
            float p0 = __builtin_amdgcn_exp2f(s_[rs][0][r]);                   \
            float p1 = __builtin_amdgcn_exp2f(s_[rs][1][r]);                   \
            int row = rg + rs * 16 + quad * 4 + r;                             \
            unsigned pk = __builtin_amdgcn_perm(                               \
                __builtin_bit_cast(unsigned, p1),                              \
                __builtin_bit_cast(unsigned, p0), 0x07060302u);                \
            *(unsigned*)&sP[row * PS + kh + 2 * l15] = pk;                     \
        }                                                                      \
    {                                                                          \
        bf16x8 aP0 = *(const bf16x8*)&sP[(rg + l15) * PS + kh + quad * 8];     \
        bf16x8 aP1 = *(const bf16x8*)&sP[(rg + 16 + l15) * PS + kh + quad * 8];\
        lacc[0] = __builtin_amdgcn_mfma_f32_16x16x32_bf16(aP0, vone, lacc[0], 0,0,0); \
        lacc[1] = __builtin_amdgcn_mfma_f32_16x16x32_bf16(aP1, vone, lacc[1], 0,0,0); \
        _Pragma("unroll")                                                      \
        for (int dt = 0; dt < 8; ++dt) {                                       \
            acc[0][dt] = __builtin_amdgcn_mfma_f32_16x16x32_bf16(aP0, CV[dt], acc[0][dt], 0,0,0); \
            acc[1][dt] = __builtin_amdgcn_mfma_f32_16x16x32_bf16(aP1, CV[dt], acc[1][dt], 0,0,0); \
        }                                                                      \
    }                                                                          \
} while (0)

    bf16x8 bkA[2][4], bvA[8], bkB[2][4], bvB[8];
    LOADKV(bkA, bvA, 0);
    for (int kk = 0; kk < nIter2; kk += 2) {
        TILE_BODY(bkA, bvA, bkB, bvB, kk);
        TILE_BODY(bkB, bvB, bkA, bvA, kk + 1);
    }
#undef TILE_BODY
#undef LOADKV

    // ---- epilogue: combine key-half partials (wh=1 publishes via LDS) ----
    if (wh == 1) {
        #pragma unroll
        for (int rs = 0; rs < 2; ++rs)
            #pragma unroll
            for (int r = 0; r < 4; ++r) {
                int lrow = rg + rs * 16 + quad * 4 + r;
                #pragma unroll
                for (int dt = 0; dt < 8; ++dt)
                    sO[lrow * 128 + dt * 16 + l15] = acc[rs][dt][r];
                if (l15 == 0) sLp[lrow] = lacc[rs][r];
            }
    }
    __syncthreads();
    if (wh == 0) {
        float* Og = O + ((size_t)b * LQ_ + q0 + rg) * DIM_;
        #pragma unroll
        for (int rs = 0; rs < 2; ++rs)
            #pragma unroll
            for (int r = 0; r < 4; ++r) {
                int lrow = rs * 16 + quad * 4 + r;
                float inv = 1.0f / (lacc[rs][r] + sLp[rg + lrow]);
                #pragma unroll
                for (int dt = 0; dt < 8; ++dt)
                    Og[(size_t)lrow * DIM_ + dt * 16 + l15] =
                        (acc[rs][dt][r] + sO[(rg + lrow) * 128 + dt * 16 + l15]) * inv;
            }
    }
}

// ================= fallback (validated R1 kernel, ws too small) =============
#define QS 136
#define VS 72
__global__ __launch_bounds__(NTH, 2) void attn_fallback(
    const float* __restrict__ Q, const float* __restrict__ K,
    const float* __restrict__ V, const float* __restrict__ Mk,
    float* __restrict__ O)
{
    __shared__ __align__(16) unsigned short sQ[64][QS];
    __shared__ __align__(16) unsigned short sK[64][QS];
    __shared__ __align__(16) unsigned short sVt[DIM_][VS];
    __shared__ __align__(16) unsigned short sPf[64][VS];
    __shared__ float sB[64];

    const int tid  = threadIdx.x;
    const int w    = tid >> 6, lane = tid & 63;
    const int quad = lane >> 4, l15 = lane & 15;
    const int bid = blockIdx.x;
    const int grp = bid >> 3;
    const int b   = (bid & 7) + 8 * (grp & 1);
    const int q0  = (grp >> 1) * 64;

    {
        const float4* Qg = (const float4*)(Q + ((size_t)b * LQ_ + q0) * DIM_);
        #pragma unroll
        for (int it = 0; it < 8; ++it) {
            int i = tid + it * NTH;
            int r = i >> 5, c4 = i & 31;
            float4 v = Qg[r * 32 + c4];
            ushort4 h = { f2bf(v.x), f2bf(v.y), f2bf(v.z), f2bf(v.w) };
            *(ushort4*)&sQ[r][c4 * 4] = h;
        }
    }
    __syncthreads();
    bf16x8 aQ[4];
    #pragma unroll
    for (int ks = 0; ks < 4; ++ks)
        aQ[ks] = *(const bf16x8*)&sQ[w * 16 + l15][ks * 32 + quad * 8];

    float m_i[4], l_i[4];
    f32x4 acc[8];
    #pragma unroll
    for (int r = 0; r < 4; ++r) { m_i[r] = -3.0e38f; l_i[r] = 0.f; }
    #pragma unroll
    for (int dt = 0; dt < 8; ++dt) acc[dt] = (f32x4){0.f, 0.f, 0.f, 0.f};

    for (int k0 = 0; k0 < LK_; k0 += 64) {
        const float4* Kg = (const float4*)(K + ((size_t)b * LK_ + k0) * DIM_);
        const float4* Vg = (const float4*)(V + ((size_t)b * LK_ + k0) * DIM_);
        #pragma unroll
        for (int it = 0; it < 8; ++it) {
            int i = tid + it * NTH;
            int r = i >> 5, c4 = i & 31;
            float4 kv = Kg[r * 32 + c4];
            ushort4 h = { f2bf(kv.x), f2bf(kv.y), f2bf(kv.z), f2bf(kv.w) };
            *(ushort4*)&sK[r][c4 * 4] = h;
            float4 vv = Vg[r * 32 + c4];
            int d = c4 * 4;
            sVt[d + 0][r] = f2bf(vv.x);
            sVt[d + 1][r] = f2bf(vv.y);
            sVt[d + 2][r] = f2bf(vv.z);
            sVt[d + 3][r] = f2bf(vv.w);
        }
        if (tid < 64) sB[tid] = Mk[k0 + tid] * NEGBIG;
        __syncthreads();

        f32x4 s[4];
        #pragma unroll
        for (int kt = 0; kt < 4; ++kt) {
            f32x4 c = (f32x4){0.f, 0.f, 0.f, 0.f};
            #pragma unroll
            for (int ks = 0; ks < 4; ++ks) {
                bf16x8 bk = *(const bf16x8*)&sK[kt * 16 + l15][ks * 32 + quad * 8];
                c = __builtin_amdgcn_mfma_f32_16x16x32_bf16(aQ[ks], bk, c, 0, 0, 0);
            }
            float bias = sB[kt * 16 + l15];
            #pragma unroll
            for (int r = 0; r < 4; ++r) s[kt][r] = c[r] * SCALE_ + bias;
        }
        #pragma unroll
        for (int r = 0; r < 4; ++r) {
            float mx = fmaxf(fmaxf(s[0][r], s[1][r]), fmaxf(s[2][r], s[3][r]));
            #pragma unroll
            for (int off = 1; off < 16; off <<= 1) mx = fmaxf(mx, __shfl_xor(mx, off));
            float mn = fmaxf(m_i[r], mx);
            float al = __expf(m_i[r] - mn);
            m_i[r] = mn;
            float rsum = 0.f;
            #pragma unroll
            for (int kt = 0; kt < 4; ++kt) {
                float p = __expf(s[kt][r] - mn);
                rsum += p;
                sPf[w * 16 + quad * 4 + r][kt * 16 + l15] = f2bf(p);
            }
            #pragma unroll
            for (int off = 1; off < 16; off <<= 1) rsum += __shfl_xor(rsum, off);
            l_i[r] = l_i[r] * al + rsum;
            #pragma unroll
            for (int dt = 0; dt < 8; ++dt) acc[dt][r] *= al;
        }
        bf16x8 aP0 = *(const bf16x8*)&sPf[w * 16 + l15][quad * 8];
        bf16x8 aP1 = *(const bf16x8*)&sPf[w * 16 + l15][32 + quad * 8];
        #pragma unroll
        for (int dt = 0; dt < 8; ++dt) {
            bf16x8 bv0 = *(const bf16x8*)&sVt[dt * 16 + l15][quad * 8];
            bf16x8 bv1 = *(const bf16x8*)&sVt[dt * 16 + l15][32 + quad * 8];
            acc[dt] = __builtin_amdgcn_mfma_f32_16x16x32_bf16(aP0, bv0, acc[dt], 0, 0, 0);
            acc[dt] = __builtin_amdgcn_mfma_f32_16x16x32_bf16(aP1, bv1, acc[dt], 0, 0, 0);
        }
        __syncthreads();
    }
    float* Og = O + ((size_t)b * LQ_ + q0 + w * 16) * DIM_;
    #pragma unroll
    for (int r = 0; r < 4; ++r) {
        float inv = 1.0f / l_i[r];
        int row = quad * 4 + r;
        #pragma unroll
        for (int dt = 0; dt < 8; ++dt)
            Og[(size_t)row * DIM_ + dt * 16 + l15] = acc[dt][r] * inv;
    }
}

extern "C" void kernel_launch(void* const* d_in, const int* in_sizes, int n_in,
                              void* d_out, int out_size, void* d_ws, size_t ws_size,
                              hipStream_t stream)
{
    const float* Q  = (const float*)d_in[0];
    const float* K  = (const float*)d_in[1];
    const float* V  = (const float*)d_in[2];
    const float* Mk = (const float*)d_in[3];
    float* O = (float*)d_out;

    const size_t seg  = (size_t)B_ * LK_ * DIM_ * 2;   // 8 MB per packed tensor
    const size_t need = 16384 + 2 * seg;               // hdr + Kb + Vtb
    if (ws_size >= need) {
        int* hdr = (int*)d_ws;                          // [0] = kept count
        unsigned short* Kb  = (unsigned short*)((char*)d_ws + 16384);
        unsigned short* Vtb = Kb + seg / 2;
        hipLaunchKernelGGL(pack_all,   dim3(512), dim3(NTH), 0, stream, K, V, Mk, hdr, Kb, Vtb);
        hipLaunchKernelGGL(attn_mfma7, dim3(512), dim3(NTH), 0, stream, Q, Kb, Vtb, hdr, O);
    } else {
        hipLaunchKernelGGL(attn_fallback, dim3(512), dim3(NTH), 0, stream, Q, K, V, Mk, O);
    }
}